// Round 1
// baseline (2108.672 us; speedup 1.0000x reference)
//
#include <hip/hip_runtime.h>
#include <math.h>

#define B 4096
#define S 32
#define D 256
#define V 50257
#define N_ALIVE 100
#define TB 64

// ---------------------------------------------------------------------------
// Kernel A: per-batch context pooling + RBF activations.
// One block (256 threads = 4 waves) per batch row.
// ---------------------------------------------------------------------------
__global__ __launch_bounds__(256) void ctx_act_kernel(
    const int*   __restrict__ token_ids,   // [B,S]
    const float* __restrict__ te,          // [V,D]
    const float* __restrict__ pe,          // [S,D]
    const float* __restrict__ q,           // [D]
    const float* __restrict__ pos,         // [N,D]
    float*       __restrict__ act)         // [B,N]
{
    __shared__ int   s_ids[S];
    __shared__ float s_scores[S];
    __shared__ float s_w[S];
    __shared__ float s_ctx[D];
    __shared__ float s_red[128];
    __shared__ float s_total;

    const int b    = blockIdx.x;
    const int tid  = threadIdx.x;
    const int lane = tid & 63;
    const int wave = tid >> 6;

    if (tid < S) s_ids[tid] = token_ids[b * S + tid];
    __syncthreads();

    // ---- attention scores: wave w handles s = 8w .. 8w+7 ----
    for (int j = 0; j < 8; ++j) {
        const int s = wave * 8 + j;
        const float* terow = te + (size_t)s_ids[s] * D;
        const float* perow = pe + (size_t)s * D;
        float p = 0.f;
        #pragma unroll
        for (int k = 0; k < 4; ++k) {
            const int d = lane + 64 * k;
            p += (terow[d] + perow[d]) * q[d];
        }
        #pragma unroll
        for (int m = 32; m >= 1; m >>= 1) p += __shfl_xor(p, m);
        if (lane == 0) s_scores[s] = p * (1.0f / 16.0f);  // / sqrt(D)
    }
    __syncthreads();

    // ---- softmax over S=32 (first 32 lanes of wave 0) ----
    if (tid < 32) {
        const float sc = s_scores[tid];
        float m = sc;
        #pragma unroll
        for (int k = 16; k >= 1; k >>= 1) m = fmaxf(m, __shfl_xor(m, k));
        const float e = expf(sc - m);
        float tot = e;
        #pragma unroll
        for (int k = 16; k >= 1; k >>= 1) tot += __shfl_xor(tot, k);
        s_w[tid] = e / tot;
    }
    __syncthreads();

    // ---- context: thread tid owns dim d = tid ----
    {
        float c = 0.f;
        for (int s = 0; s < S; ++s) {
            c += s_w[s] * (te[(size_t)s_ids[s] * D + tid] + pe[(size_t)s * D + tid]);
        }
        s_ctx[tid] = c;
    }
    __syncthreads();

    // ---- RBF activations: thread n = tid (n < 100) ----
    float a = 0.f;
    if (tid < N_ALIVE) {
        const float4* p4 = (const float4*)(pos + (size_t)tid * D);
        const float4* c4 = (const float4*)s_ctx;
        float d2 = 0.f;
        #pragma unroll 8
        for (int dd = 0; dd < D / 4; ++dd) {
            const float4 cv = c4[dd];
            const float4 pv = p4[dd];
            const float dx = cv.x - pv.x;
            const float dy = cv.y - pv.y;
            const float dz = cv.z - pv.z;
            const float dw = cv.w - pv.w;
            d2 += dx * dx + dy * dy + dz * dz + dw * dw;
        }
        a = expf(-2.0f * d2);  // exp(-d2 / (2 * 0.5^2))
    }
    if (tid < 128) s_red[tid] = (tid < N_ALIVE) ? a : 0.f;
    __syncthreads();
    if (tid < 64) s_red[tid] += s_red[tid + 64];
    __syncthreads();
    if (tid < 64) {
        float v = s_red[tid];
        #pragma unroll
        for (int k = 32; k >= 1; k >>= 1) v += __shfl_xor(v, k);
        if (tid == 0) s_total = v;
    }
    __syncthreads();
    if (tid < N_ALIVE) act[(size_t)b * N_ALIVE + tid] = a / (s_total + 1e-8f);
}

// ---------------------------------------------------------------------------
// Kernel B: logits = act[B,100] @ W[100,V].
// Thread = one vocab column v (coalesced loads/stores of W/out).
// Block covers TB=64 batch rows; act read via block-uniform addresses
// (should compile to s_load_dwordx4; FMA operand comes from SGPRs).
// ---------------------------------------------------------------------------
__global__ __launch_bounds__(256) void logits_kernel(
    const float* __restrict__ act,   // [B, N]
    const float* __restrict__ W,     // [N, V]
    float*       __restrict__ out)   // [B, V]
{
    const int v  = blockIdx.x * 256 + threadIdx.x;
    const int b0 = blockIdx.y * TB;
    const bool valid = (v < V);

    float acc[TB];
    #pragma unroll
    for (int i = 0; i < TB; ++i) acc[i] = 0.f;

    for (int kc = 0; kc < N_ALIVE / 4; ++kc) {
        float w0 = 0.f, w1 = 0.f, w2 = 0.f, w3 = 0.f;
        if (valid) {
            w0 = W[(size_t)(4 * kc + 0) * V + v];
            w1 = W[(size_t)(4 * kc + 1) * V + v];
            w2 = W[(size_t)(4 * kc + 2) * V + v];
            w3 = W[(size_t)(4 * kc + 3) * V + v];
        }
        #pragma unroll
        for (int i = 0; i < TB; ++i) {
            // uniform address across the block -> scalar load
            const float4 a = *(const float4*)(act + (size_t)(b0 + i) * N_ALIVE + 4 * kc);
            acc[i] = fmaf(a.x, w0, acc[i]);
            acc[i] = fmaf(a.y, w1, acc[i]);
            acc[i] = fmaf(a.z, w2, acc[i]);
            acc[i] = fmaf(a.w, w3, acc[i]);
        }
    }

    if (valid) {
        #pragma unroll
        for (int i = 0; i < TB; ++i) {
            out[(size_t)(b0 + i) * V + v] = acc[i];
        }
    }
}

// ---------------------------------------------------------------------------
extern "C" void kernel_launch(void* const* d_in, const int* in_sizes, int n_in,
                              void* d_out, int out_size, void* d_ws, size_t ws_size,
                              hipStream_t stream) {
    const int*   token_ids = (const int*)d_in[0];
    const float* te        = (const float*)d_in[1];
    const float* pe        = (const float*)d_in[2];
    const float* q         = (const float*)d_in[3];
    const float* pos       = (const float*)d_in[4];
    const float* W         = (const float*)d_in[5];
    float*       out       = (float*)d_out;
    float*       act       = (float*)d_ws;   // B*N floats = 1.6 MB

    ctx_act_kernel<<<dim3(B), dim3(256), 0, stream>>>(token_ids, te, pe, q, pos, act);

    dim3 gridB((V + 255) / 256, B / TB);
    logits_kernel<<<gridB, dim3(256), 0, stream>>>(act, W, out);
}

// Round 2
// 1239.653 us; speedup vs baseline: 1.7010x; 1.7010x over previous
//
#include <hip/hip_runtime.h>
#include <hip/hip_bf16.h>
#include <math.h>

#define B 4096
#define S 32
#define D 256
#define V 50257
#define N_ALIVE 100
#define K_PAD 128          // K=100 zero-padded to 128 (4 x mfma K=32)
#define V_PAD 50432        // 197 * 256

typedef __attribute__((ext_vector_type(8))) short short8;   // 8 bf16 (4 VGPRs)
typedef __attribute__((ext_vector_type(4))) float float4v;  // 4 fp32 acc

// ---------------------------------------------------------------------------
// Kernel A: per-batch context pooling + RBF activations.
// Single pass: embeds staged in LDS once, then scores/softmax/context/RBF.
// Writes the bf16 A-matrix [B, K_PAD] (cols 100..127 zero).
// One block (256 threads = 4 waves) per batch row.
// ---------------------------------------------------------------------------
__global__ __launch_bounds__(256) void ctx_act_kernel(
    const int*   __restrict__ token_ids,   // [B,S]
    const float* __restrict__ te,          // [V,D]
    const float* __restrict__ pe,          // [S,D]
    const float* __restrict__ q,           // [D]
    const float* __restrict__ pos,         // [N,D]
    __hip_bfloat16* __restrict__ A)        // [B, K_PAD]
{
    __shared__ __align__(16) float s_emb[S][D];   // 32 KB
    __shared__ int   s_ids[S];
    __shared__ float s_scores[S];
    __shared__ float s_w[S];
    __shared__ __align__(16) float s_ctx[D];
    __shared__ float s_red[128];
    __shared__ float s_total;

    const int b    = blockIdx.x;
    const int tid  = threadIdx.x;
    const int lane = tid & 63;
    const int wave = tid >> 6;

    if (tid < S) s_ids[tid] = token_ids[b * S + tid];
    __syncthreads();

    // ---- embeds -> LDS + attention scores (wave w handles s = 8w..8w+7) ----
    const float4 qv = *(const float4*)(q + lane * 4);
    #pragma unroll
    for (int j = 0; j < 8; ++j) {
        const int s = wave * 8 + j;
        const float4 t4 = *(const float4*)(te + (size_t)s_ids[s] * D + lane * 4);
        const float4 p4 = *(const float4*)(pe + (size_t)s * D + lane * 4);
        float4 e4;
        e4.x = t4.x + p4.x; e4.y = t4.y + p4.y;
        e4.z = t4.z + p4.z; e4.w = t4.w + p4.w;
        *(float4*)&s_emb[s][lane * 4] = e4;
        float p = e4.x * qv.x + e4.y * qv.y + e4.z * qv.z + e4.w * qv.w;
        #pragma unroll
        for (int m = 32; m >= 1; m >>= 1) p += __shfl_xor(p, m);
        if (lane == 0) s_scores[s] = p * 0.0625f;   // 1/sqrt(256)
    }
    __syncthreads();

    // ---- softmax over S=32 (first 32 lanes of wave 0) ----
    if (tid < 32) {
        const float sc = s_scores[tid];
        float m = sc;
        #pragma unroll
        for (int k = 16; k >= 1; k >>= 1) m = fmaxf(m, __shfl_xor(m, k));
        const float e = expf(sc - m);
        float tot = e;
        #pragma unroll
        for (int k = 16; k >= 1; k >>= 1) tot += __shfl_xor(tot, k);
        s_w[tid] = e / tot;
    }
    __syncthreads();

    // ---- context: thread tid owns dim d = tid (LDS reads, 2-way = free) ----
    {
        float c = 0.f;
        #pragma unroll
        for (int s = 0; s < S; ++s) c += s_w[s] * s_emb[s][tid];
        s_ctx[tid] = c;
    }
    __syncthreads();

    // ---- RBF activations: thread n = tid (n < 100) ----
    float a = 0.f;
    if (tid < N_ALIVE) {
        const float4* p4 = (const float4*)(pos + (size_t)tid * D);
        const float4* c4 = (const float4*)s_ctx;
        float d2 = 0.f;
        #pragma unroll 8
        for (int dd = 0; dd < D / 4; ++dd) {
            const float4 cv = c4[dd];
            const float4 pv = p4[dd];
            const float dx = cv.x - pv.x;
            const float dy = cv.y - pv.y;
            const float dz = cv.z - pv.z;
            const float dw = cv.w - pv.w;
            d2 += dx * dx + dy * dy + dz * dz + dw * dw;
        }
        a = expf(-2.0f * d2);   // exp(-d2 / (2 * 0.5^2))
    }
    if (tid < 128) s_red[tid] = (tid < N_ALIVE) ? a : 0.f;
    __syncthreads();
    if (tid < 64) s_red[tid] += s_red[tid + 64];
    __syncthreads();
    if (tid < 64) {
        float v = s_red[tid];
        #pragma unroll
        for (int k = 32; k >= 1; k >>= 1) v += __shfl_xor(v, k);
        if (tid == 0) s_total = v;
    }
    __syncthreads();
    if (tid < K_PAD) {
        const float val = (tid < N_ALIVE) ? (a / (s_total + 1e-8f)) : 0.f;
        A[(size_t)b * K_PAD + tid] = __float2bfloat16(val);
    }
}

// ---------------------------------------------------------------------------
// Transpose/convert: Wt[v][k] = bf16(W[k][v]), zero-padded to [V_PAD, K_PAD].
// Coalesced W reads (threads sweep v for fixed k). grid = (197, 8).
// ---------------------------------------------------------------------------
__global__ __launch_bounds__(256) void transpose_w(
    const float* __restrict__ W,            // [N_ALIVE, V]
    __hip_bfloat16* __restrict__ Wt)        // [V_PAD, K_PAD]
{
    const int v  = blockIdx.x * 256 + threadIdx.x;   // < V_PAD by grid
    const int k0 = blockIdx.y * 16;
    __hip_bfloat16* dst = Wt + (size_t)v * K_PAD + k0;
    #pragma unroll
    for (int kk = 0; kk < 16; ++kk) {
        const int k = k0 + kk;
        const float w = (v < V && k < N_ALIVE) ? W[(size_t)k * V + v] : 0.f;
        dst[kk] = __float2bfloat16(w);
    }
}

// ---------------------------------------------------------------------------
// Kernel B: out[B,V] = A[B,K_PAD] @ Wt[V_PAD,K_PAD]^T via bf16 MFMA.
// Block = 256 threads (4 waves). Block tile: 64 M-rows x 256 N-cols.
// Wave tile per n-iter: 16 N-cols; MT=4 m-tiles of 16 rows.
// mfma_f32_16x16x32_bf16 layouts (verified in guide §3):
//   A: m = lane&15, k = (lane>>4)*8 + j      (8 bf16 contiguous in K -> 16B load)
//   B: n = lane&15, k = (lane>>4)*8 + j      (contiguous in Wt row -> 16B load)
//   C/D: col = lane&15, row = (lane>>4)*4 + reg
// ---------------------------------------------------------------------------
#define MT 4
#define NITER 4

__global__ __launch_bounds__(256) void gemm_mfma(
    const __hip_bfloat16* __restrict__ A,    // [B, K_PAD]
    const __hip_bfloat16* __restrict__ Wt,   // [V_PAD, K_PAD]
    float* __restrict__ out)                 // [B, V]
{
    const int tid  = threadIdx.x;
    const int lane = tid & 63;
    const int wave = tid >> 6;
    const int quad = lane >> 4;
    const int l16  = lane & 15;
    const int y0   = blockIdx.y * (MT * 16);
    const int x0   = blockIdx.x * 256;

    // A fragments: same for all 4 waves (L2-hot, 1 MB total).
    short8 a_frag[MT][4];
    #pragma unroll
    for (int mt = 0; mt < MT; ++mt) {
        const int row = y0 + mt * 16 + l16;
        const short* ap = (const short*)(A + (size_t)row * K_PAD);
        #pragma unroll
        for (int ks = 0; ks < 4; ++ks)
            a_frag[mt][ks] = *(const short8*)(ap + ks * 32 + quad * 8);
    }

    #pragma unroll
    for (int it = 0; it < NITER; ++it) {
        const int col = x0 + it * 64 + wave * 16 + l16;
        const short* bp = (const short*)(Wt + (size_t)col * K_PAD);
        short8 b_frag[4];
        #pragma unroll
        for (int ks = 0; ks < 4; ++ks)
            b_frag[ks] = *(const short8*)(bp + ks * 32 + quad * 8);

        #pragma unroll
        for (int mt = 0; mt < MT; ++mt) {
            float4v acc = {0.f, 0.f, 0.f, 0.f};
            #pragma unroll
            for (int ks = 0; ks < 4; ++ks)
                acc = __builtin_amdgcn_mfma_f32_16x16x32_bf16(
                          a_frag[mt][ks], b_frag[ks], acc, 0, 0, 0);
            if (col < V) {
                #pragma unroll
                for (int r = 0; r < 4; ++r)
                    out[(size_t)(y0 + mt * 16 + quad * 4 + r) * V + col] = acc[r];
            }
        }
    }
}

// ---------------------------------------------------------------------------
// Fallback (ws too small for Wt): fp32 VALU, TB=16 rows in VGPRs (no spill).
// ---------------------------------------------------------------------------
__global__ __launch_bounds__(256) void logits_fallback(
    const __hip_bfloat16* __restrict__ A,   // [B, K_PAD]
    const float* __restrict__ W,            // [N_ALIVE, V]
    float* __restrict__ out)                // [B, V]
{
    const int v  = blockIdx.x * 256 + threadIdx.x;
    const int b0 = blockIdx.y * 16;
    const bool valid = (v < V);

    float acc[16];
    #pragma unroll
    for (int i = 0; i < 16; ++i) acc[i] = 0.f;

    for (int k = 0; k < N_ALIVE; ++k) {
        const float w = valid ? W[(size_t)k * V + v] : 0.f;
        #pragma unroll
        for (int i = 0; i < 16; ++i) {
            const float a = __bfloat162float(A[(size_t)(b0 + i) * K_PAD + k]);
            acc[i] = fmaf(a, w, acc[i]);
        }
    }
    if (valid) {
        #pragma unroll
        for (int i = 0; i < 16; ++i)
            out[(size_t)(b0 + i) * V + v] = acc[i];
    }
}

// ---------------------------------------------------------------------------
extern "C" void kernel_launch(void* const* d_in, const int* in_sizes, int n_in,
                              void* d_out, int out_size, void* d_ws, size_t ws_size,
                              hipStream_t stream) {
    const int*   token_ids = (const int*)d_in[0];
    const float* te        = (const float*)d_in[1];
    const float* pe        = (const float*)d_in[2];
    const float* q         = (const float*)d_in[3];
    const float* pos       = (const float*)d_in[4];
    const float* W         = (const float*)d_in[5];
    float*       out       = (float*)d_out;

    __hip_bfloat16* Abf = (__hip_bfloat16*)d_ws;                  // 1 MiB
    const size_t offW   = (size_t)B * K_PAD * sizeof(__hip_bfloat16);
    __hip_bfloat16* Wt  = (__hip_bfloat16*)((char*)d_ws + offW);  // ~12.9 MB
    const size_t need   = offW + (size_t)V_PAD * K_PAD * sizeof(__hip_bfloat16);

    ctx_act_kernel<<<dim3(B), dim3(256), 0, stream>>>(token_ids, te, pe, q, pos, Abf);

    if (ws_size >= need) {
        transpose_w<<<dim3(V_PAD / 256, 8), dim3(256), 0, stream>>>(W, Wt);
        gemm_mfma<<<dim3(V_PAD / 256, B / (MT * 16)), dim3(256), 0, stream>>>(Abf, Wt, out);
    } else {
        logits_fallback<<<dim3(V_PAD / 256, B / 16), dim3(256), 0, stream>>>(Abf, W, out);
    }
}